// Round 9
// baseline (73.183 us; speedup 1.0000x reference)
//
#include <hip/hip_runtime.h>
#include <hip/hip_bf16.h>
#include <stdint.h>

typedef __attribute__((ext_vector_type(8))) short short8;
typedef __attribute__((ext_vector_type(16))) float f32x16;

namespace {
constexpr int NB = 4, NL = 2048, NH = 8, NE = 64, ND = 64;
constexpr float KS = 0.125f * 1.44269504f;   // 1/sqrt(E)*log2(e): exp2-domain logits
constexpr int RECSZ32 = 2080;                // per-unit record: O^T 64*32 + l 32 (floats)
constexpr int NUNIT   = 160;                 // units per bh (closed-form decomposition)
constexpr int NCHUNK = 40;                   // fallback path constants
constexpr int RECSZ  = 8320;
constexpr int KSTEP  = 64 * NH * NE;
}

// -------- fallback chunk tables (R6 path) --------
__device__ const unsigned char TG[40] = {
  3,7,7,10,11,11,11,14,14,15,15,15,15,
  6,6,9,9,10,10,12,12,13,13,13,13,14,14,
  2,5,5,8,8,8,9,12,12,
  4,4,1,0};
__device__ const unsigned char TT0[40] = {
  0,0,16,0,0,16,32,0,16,0,16,32,48,
  0,14,0,14,16,30,0,14,0,14,28,42,32,46,
  0,0,12,0,12,24,28,28,40,
  0,10,0,0};
__device__ const unsigned char TT1[40] = {
  16,16,32,16,16,32,48,16,32,16,32,48,64,
  14,28,14,28,30,44,14,28,14,28,42,56,46,60,
  12,12,24,12,24,36,40,40,52,
  10,20,8,4};
__device__ const unsigned char TREC[40] = {
  3,10,11,18,21,22,23,32,33,36,37,38,39,
  8,9,15,16,19,20,24,25,28,29,30,31,34,35,
  2,6,7,12,13,14,17,26,27,
  4,5,1,0};
__device__ const unsigned char CUMD[16] = {0,1,2,3,4,6,8,10,12,15,18,21,24,28,32,36};
__device__ const unsigned char NCHD[16] = {1,1,1,1,2,2,2,2,3,3,3,3,4,4,4,4};

__device__ __forceinline__ ushort bfb(float x) {
  __hip_bfloat16 b(x);
  return __builtin_bit_cast(ushort, b);
}
__device__ __forceinline__ uint32_t pkbf(float lo, float hi) {
  return (uint32_t)bfb(lo) | ((uint32_t)bfb(hi) << 16);
}

// image layouts (bf16): K: round*8192 + key*128 + ((2e) ^ ((key&7)<<4)), key,e in [0,64)
//                       V: round*8192 + d*128   + ((2k) ^ ((d&7)<<4)),   d,k   in [0,64)

// -------- convert: K,V fp32 -> bf16 image (one-shot, memory-bound; R8-proven) --------
__global__ __launch_bounds__(256)
void convkv(const float* __restrict__ Kg, const float* __restrict__ Vg,
            char* __restrict__ kimg, char* __restrict__ vimg)
{
  const int id = blockIdx.x;          // 1024 = 32 bh * 32 rounds
  const int kr = id & 31, bh = id >> 5;
  const int b = bh >> 3, h = bh & 7;
  const int tid = threadIdx.x;

  __shared__ float vt[64 * 64];

  const int key_in = tid >> 2;
  const int e0     = (tid & 3) * 16;
  {
    const float* vp = Vg + (((size_t)b * NL + kr * 64 + key_in) * NH + h) * ND + e0;
    float* dst = vt + key_in * 64 + e0;
    *(float4*)(dst)      = *(const float4*)(vp);
    *(float4*)(dst + 4)  = *(const float4*)(vp + 4);
    *(float4*)(dst + 8)  = *(const float4*)(vp + 8);
    *(float4*)(dst + 12) = *(const float4*)(vp + 12);
  }
  {
    const float* kp = Kg + (((size_t)b * NL + kr * 64 + key_in) * NH + h) * NE + e0;
    float4 a = *(const float4*)kp,      c = *(const float4*)(kp + 4);
    float4 d2 = *(const float4*)(kp + 8), f = *(const float4*)(kp + 12);
    uint4 wA = { pkbf(a.x,a.y), pkbf(a.z,a.w), pkbf(c.x,c.y), pkbf(c.z,c.w) };
    uint4 wB = { pkbf(d2.x,d2.y), pkbf(d2.z,d2.w), pkbf(f.x,f.y), pkbf(f.z,f.w) };
    char* ko = kimg + ((size_t)bh * 32 + kr) * 8192 + key_in * 128;
    const int C = (key_in & 7) << 4;
    *(uint4*)(ko + ((2 * e0)      ^ C)) = wA;
    *(uint4*)(ko + ((2 * e0 + 16) ^ C)) = wB;
  }
  __syncthreads();
  char* vo0 = vimg + ((size_t)bh * 32 + kr) * 8192;
  #pragma unroll
  for (int it = 0; it < 2; ++it) {
    int lin = it * 256 + tid;
    int d = lin & 63, kg = lin >> 6;
    const float* col = vt + kg * 8 * 64 + d;
    uint4 w = { pkbf(col[0], col[64]),    pkbf(col[128], col[192]),
                pkbf(col[256], col[320]), pkbf(col[384], col[448]) };
    *(uint4*)(vo0 + d * 128 + ((kg * 16) ^ ((d & 7) << 4))) = w;
  }
}

// -------- main: wave-autonomous, barrier-free, LDS-free, direct image reads --------
__global__ __launch_bounds__(256)
void sattn_wave(const float* __restrict__ Qg, const char* __restrict__ kimg,
                const char* __restrict__ vimg, float* __restrict__ W)
{
  const int id   = blockIdx.x;        // 1280 = 32 bh * 40 ublk ; id%8 = bh%8 -> XCD pin
  const int bh   = id & 31;
  const int ublk = id >> 5;
  const int b = bh >> 3, h = bh & 7;

  const int tid  = threadIdx.x;
  const int wave = tid >> 6;
  const int lane = tid & 63;
  const int ln31 = lane & 31;
  const int hi   = lane >> 5;

  // unit u -> (strip s, sub-chunk k): closed form over 4 groups of 16 strips
  const int u = ublk * 4 + wave;      // 0..159
  int G, s, k;
  if      (u < 16)  { G = 0; s = u;                 k = 0; }
  else if (u < 48)  { G = 1; s = 16 + (u - 16) / 2; k = (u - 16) % 2; }
  else if (u < 96)  { G = 2; s = 32 + (u - 48) / 3; k = (u - 48) % 3; }
  else              { G = 3; s = 48 + (u - 96) / 4; k = (u - 96) % 4; }
  (void)G;
  const int t0u = 16 * k;
  const int n   = s + 1;                          // causal tile count for this strip
  const int t1u = (16 * (k + 1) < n) ? 16 * (k + 1) : n;

  float* rec = W + ((size_t)bh * NUNIT + u) * RECSZ32;

  const int q0w = s * 32;
  const int qi  = q0w + ln31;
  const int rsw = (ln31 & 7) << 4;
  const char* kb_img = kimg + (size_t)bh * 32 * 8192;
  const char* vb_img = vimg + (size_t)bh * 32 * 8192;

  // Q fragments, pre-scaled by KS
  short8 qf[4];
  {
    const float* qp = Qg + (((size_t)b * NL + qi) * NH + h) * NE;
    #pragma unroll
    for (int st = 0; st < 4; ++st) {
      const float* qpe = qp + st * 16 + hi * 8;
      union { short8 v; uint32_t u[4]; } f;
      #pragma unroll
      for (int j = 0; j < 4; ++j)
        f.u[j] = pkbf(qpe[2 * j] * KS, qpe[2 * j + 1] * KS);
      qf[st] = f.v;
    }
  }

  f32x16 acc0, acc1;
  #pragma unroll
  for (int i = 0; i < 16; ++i) { acc0[i] = 0.f; acc1[i] = 0.f; }
  float ls = 0.f;

  for (int t = t0u; t < t1u; ++t) {
    const int kv0 = t * 32;
    const char* kbase = kb_img + (size_t)(t >> 1) * 8192 + ((t & 1) * 32 + ln31) * 128;
    const char* vbase = vb_img + (size_t)(t >> 1) * 8192;
    const int   vsub  = (t & 1) * 64;

    // V-frag loads issued first: independent of QK chain -> in flight under it
    short8 a00 = *(const short8*)(vbase + ln31 * 128        + ((vsub      + hi * 16) ^ rsw));
    short8 a01 = *(const short8*)(vbase + ln31 * 128        + ((vsub + 32 + hi * 16) ^ rsw));
    short8 a10 = *(const short8*)(vbase + (32 + ln31) * 128 + ((vsub      + hi * 16) ^ rsw));
    short8 a11 = *(const short8*)(vbase + (32 + ln31) * 128 + ((vsub + 32 + hi * 16) ^ rsw));

    // S^T = K · (KS*Q)^T
    f32x16 sv;
    #pragma unroll
    for (int i = 0; i < 16; ++i) sv[i] = 0.f;
    #pragma unroll
    for (int st = 0; st < 4; ++st) {
      short8 kf = *(const short8*)(kbase + ((st * 32 + hi * 16) ^ rsw));
      sv = __builtin_amdgcn_mfma_f32_32x32x16_bf16(kf, qf[st], sv, 0, 0, 0);
    }

    // masks + P = exp2(logit), fixed max m=0
    const int delta = q0w - kv0;
    const int qrelh = (qi - kv0) - 4 * hi;
    float ps0 = 0.f, ps1 = 0.f;
    if (t == s) {             // diagonal: causal + pow2
      #pragma unroll
      for (int r = 0; r < 16; ++r) {
        const int cr = (r & 3) + 8 * (r >> 2);
        int diff = qrelh - cr;
        float lg = sv[r];
        bool p2 = (diff > 1) & ((diff & (diff - 1)) == 0);
        lg = p2 ? 0.f : lg;
        lg = (diff < 0) ? -__builtin_inff() : lg;
        float p = exp2f(lg);
        sv[r] = p; (r & 1 ? ps1 : ps0) += p;
      }
    } else {
      int pmax = 1 << (31 - __clz(delta + 31));
      if (pmax >= delta - 31) {    // pow2 stride window intersects tile
        #pragma unroll
        for (int r = 0; r < 16; ++r) {
          const int cr = (r & 3) + 8 * (r >> 2);
          int diff = qrelh - cr;
          bool p2 = (diff > 1) & ((diff & (diff - 1)) == 0);
          float p = exp2f(p2 ? 0.f : sv[r]);
          sv[r] = p; (r & 1 ? ps1 : ps0) += p;
        }
      } else {                     // clean: bare exp2
        #pragma unroll
        for (int r = 0; r < 16; ++r) {
          float p = exp2f(sv[r]);
          sv[r] = p; (r & 1 ? ps1 : ps0) += p;
        }
      }
    }
    ls += ps0 + ps1;

    // pack P -> bf16 fragments (4 shfls)
    uint32_t w0 = pkbf(sv[0],  sv[1]),  w1 = pkbf(sv[2],  sv[3]);
    uint32_t w2 = pkbf(sv[4],  sv[5]),  w3 = pkbf(sv[6],  sv[7]);
    uint32_t w4 = pkbf(sv[8],  sv[9]),  w5 = pkbf(sv[10], sv[11]);
    uint32_t w6 = pkbf(sv[12], sv[13]), w7 = pkbf(sv[14], sv[15]);
    uint32_t y0 = __shfl_xor(hi ? w0 : w2, 32);
    uint32_t y1 = __shfl_xor(hi ? w1 : w3, 32);
    uint32_t y2 = __shfl_xor(hi ? w4 : w6, 32);
    uint32_t y3 = __shfl_xor(hi ? w5 : w7, 32);
    union { short8 v; uint32_t u[4]; } f0, f1;
    if (hi == 0) {
      f0.u[0] = w0; f0.u[1] = w1; f0.u[2] = y0; f0.u[3] = y1;   // keys 0..15
      f1.u[0] = w4; f1.u[1] = w5; f1.u[2] = y2; f1.u[3] = y3;   // keys 16..31
    } else {
      f0.u[0] = y0; f0.u[1] = y1; f0.u[2] = w2; f0.u[3] = w3;
      f1.u[0] = y2; f1.u[1] = y3; f1.u[2] = w6; f1.u[3] = w7;
    }

    // O^T += V^T . P^T
    acc0 = __builtin_amdgcn_mfma_f32_32x32x16_bf16(a00, f0.v, acc0, 0, 0, 0);
    acc0 = __builtin_amdgcn_mfma_f32_32x32x16_bf16(a01, f1.v, acc0, 0, 0, 0);
    acc1 = __builtin_amdgcn_mfma_f32_32x32x16_bf16(a10, f0.v, acc1, 0, 0, 0);
    acc1 = __builtin_amdgcn_mfma_f32_32x32x16_bf16(a11, f1.v, acc1, 0, 0, 0);
  }

  // epilogue: unnormalized O^T partial + l
  ls += __shfl_xor(ls, 32);
  #pragma unroll
  for (int r = 0; r < 16; ++r) {
    int d = (r & 3) + 8 * (r >> 2) + 4 * hi;
    rec[d * 32 + ln31]        = acc0[r];
    rec[(32 + d) * 32 + ln31] = acc1[r];
  }
  if (hi == 0) rec[2048 + ln31] = ls;
}

// -------- combine: per (bh, strip): sum <=4 unit records, normalize, transpose --------
__global__ __launch_bounds__(256)
void sattn_combine32(const float* __restrict__ W, float* __restrict__ Og)
{
  const int id = blockIdx.x;             // 2048 = 32 bh * 64 strips
  const int s  = id & 63, bh = id >> 6;
  const int b = bh >> 3, h = bh & 7;
  const int tid = threadIdx.x;

  const int G = s >> 4, i = s & 15;
  const int cum = 8 * G * (G + 1) + i * (G + 1);
  const int nc  = G + 1;
  const float* rec0 = W + ((size_t)bh * NUNIT + cum) * RECSZ32;

  __shared__ float sd[64][33];
  __shared__ float Lq[32];

  {
    int d = tid >> 2, q4 = (tid & 3) * 8;
    float4 a0 = {0,0,0,0}, a1 = {0,0,0,0};
    for (int c = 0; c < nc; ++c) {
      const float* rp = rec0 + (size_t)c * RECSZ32 + d * 32 + q4;
      float4 v0 = *(const float4*)rp, v1 = *(const float4*)(rp + 4);
      a0.x += v0.x; a0.y += v0.y; a0.z += v0.z; a0.w += v0.w;
      a1.x += v1.x; a1.y += v1.y; a1.z += v1.z; a1.w += v1.w;
    }
    sd[d][q4+0] = a0.x; sd[d][q4+1] = a0.y; sd[d][q4+2] = a0.z; sd[d][q4+3] = a0.w;
    sd[d][q4+4] = a1.x; sd[d][q4+5] = a1.y; sd[d][q4+6] = a1.z; sd[d][q4+7] = a1.w;
  }
  if (tid < 32) {
    float a = 0.f;
    for (int c = 0; c < nc; ++c) a += rec0[(size_t)c * RECSZ32 + 2048 + tid];
    Lq[tid] = 1.0f / a;
  }
  __syncthreads();
  {
    int q = tid >> 3, d8 = (tid & 7) * 8;
    float l = Lq[q];
    float4 o0 = { sd[d8+0][q]*l, sd[d8+1][q]*l, sd[d8+2][q]*l, sd[d8+3][q]*l };
    float4 o1 = { sd[d8+4][q]*l, sd[d8+5][q]*l, sd[d8+6][q]*l, sd[d8+7][q]*l };
    float* op = Og + (((size_t)b * NL + s * 32 + q) * NH + h) * ND + d8;
    *(float4*)op = o0; *(float4*)(op + 4) = o1;
  }
}

// ======== fallback path (R6-proven register-staged; used only if ws too small) ========
#define LD(RR) do {                                                         \
    const float* kp_ = kpp + (size_t)(RR) * KSTEP;                          \
    const float* vp_ = vpp + (size_t)(RR) * KSTEP;                          \
    kx0 = *(const float4*)(kp_);      kx1 = *(const float4*)(kp_ + 4);      \
    kx2 = *(const float4*)(kp_ + 8);  kx3 = *(const float4*)(kp_ + 12);     \
    vx0 = *(const float4*)(vp_);               vx1 = *(const float4*)(vp_ + NH*ND); \
    vx2 = *(const float4*)(vp_ + 2*NH*ND);     vx3 = *(const float4*)(vp_ + 3*NH*ND); \
  } while (0)

#define STG(KB, VB) do {                                                    \
    uint4 kwA = { pkbf(kx0.x,kx0.y), pkbf(kx0.z,kx0.w),                     \
                  pkbf(kx1.x,kx1.y), pkbf(kx1.z,kx1.w) };                   \
    uint4 kwB = { pkbf(kx2.x,kx2.y), pkbf(kx2.z,kx2.w),                     \
                  pkbf(kx3.x,kx3.y), pkbf(kx3.z,kx3.w) };                   \
    *(uint4*)((KB) + krow*128 + ( kcol2        ^ kswz)) = kwA;              \
    *(uint4*)((KB) + krow*128 + ((kcol2 + 16)  ^ kswz)) = kwB;              \
    _Pragma("unroll")                                                       \
    for (int j_ = 0; j_ < 4; ++j_) {                                        \
      int d_ = vd0 + j_;                                                    \
      char* vr_ = (VB) + d_*128;                                            \
      int vs_ = (d_ & 7) << 4;                                              \
      *(uint32_t*)(vr_ + ((vk0*2    ) ^ vs_)) = pkbf(vx0[j_], vx1[j_]);     \
      *(uint32_t*)(vr_ + ((vk0*2 + 4) ^ vs_)) = pkbf(vx2[j_], vx3[j_]);     \
    }                                                                       \
  } while (0)

#define COMPUTE(TT, SUB, KB, VB) do {                                       \
    const int kv0_ = (TT) * 32;                                             \
    f32x16 s;                                                               \
    _Pragma("unroll")                                                       \
    for (int i_ = 0; i_ < 16; ++i_) s[i_] = 0.f;                            \
    { const char* kb_ = (const char*)(KB) + ((SUB)*32 + ln31) * 128;        \
      _Pragma("unroll")                                                     \
      for (int st_ = 0; st_ < 4; ++st_) {                                   \
        short8 kf_ = *(const short8*)(kb_ + ((st_*32 + hi*16) ^ rsw));      \
        s = __builtin_amdgcn_mfma_f32_32x32x16_bf16(kf_, qf[st_], s, 0,0,0);\
      } }                                                                   \
    const int delta_ = q0w - kv0_;                                          \
    const int qrelh_ = (qi - kv0_) - 4 * hi;                                \
    if ((TT) == tw) {                                                       \
      _Pragma("unroll")                                                     \
      for (int r_ = 0; r_ < 16; ++r_) {                                     \
        const int cr_ = (r_ & 3) + 8 * (r_ >> 2);                           \
        int diff_ = qrelh_ - cr_;                                           \
        float lg_ = s[r_];                                                  \
        bool p2_ = (diff_ > 1) & ((diff_ & (diff_ - 1)) == 0);              \
        lg_ = p2_ ? 0.f : lg_;                                              \
        lg_ = (diff_ < 0) ? -__builtin_inff() : lg_;                        \
        s[r_] = exp2f(lg_);                                                 \
      }                                                                     \
    } else {                                                                \
      int pmax_ = 1 << (31 - __clz(delta_ + 31));                           \
      if (pmax_ >= delta_ - 31) {                                           \
        _Pragma("unroll")                                                   \
        for (int r_ = 0; r_ < 16; ++r_) {                                   \
          const int cr_ = (r_ & 3) + 8 * (r_ >> 2);                         \
          int diff_ = qrelh_ - cr_;                                         \
          bool p2_ = (diff_ > 1) & ((diff_ & (diff_ - 1)) == 0);            \
          s[r_] = exp2f(p2_ ? 0.f : s[r_]);                                 \
        }                                                                   \
      } else {                                                              \
        _Pragma("unroll")                                                   \
        for (int r_ = 0; r_ < 16; ++r_) s[r_] = exp2f(s[r_]);               \
      }                                                                     \
    }                                                                       \
    uint32_t w0_ = pkbf(s[0],  s[1]),  w1_ = pkbf(s[2],  s[3]);             \
    uint32_t w2_ = pkbf(s[4],  s[5]),  w3_ = pkbf(s[6],  s[7]);             \
    uint32_t w4_ = pkbf(s[8],  s[9]),  w5_ = pkbf(s[10], s[11]);            \
    uint32_t w6_ = pkbf(s[12], s[13]), w7_ = pkbf(s[14], s[15]);            \
    uint32_t y0_ = __shfl_xor(hi ? w0_ : w2_, 32);                          \
    uint32_t y1_ = __shfl_xor(hi ? w1_ : w3_, 32);                          \
    uint32_t y2_ = __shfl_xor(hi ? w4_ : w6_, 32);                          \
    uint32_t y3_ = __shfl_xor(hi ? w5_ : w7_, 32);                          \
    union { short8 v; uint32_t u[4]; } f0_, f1_;                            \
    if (hi == 0) {                                                          \
      f0_.u[0] = w0_; f0_.u[1] = w1_; f0_.u[2] = y0_; f0_.u[3] = y1_;       \
      f1_.u[0] = w4_; f1_.u[1] = w5_; f1_.u[2] = y2_; f1_.u[3] = y3_;       \
    } else {                                                                \
      f0_.u[0] = y0_; f0_.u[1] = y1_; f0_.u[2] = w2_; f0_.u[3] = w3_;       \
      f1_.u[0] = y2_; f1_.u[1] = y3_; f1_.u[2] = w6_; f1_.u[3] = w7_;       \
    }                                                                       \
    { const char* vr0_ = (const char*)(VB) + ln31 * 128;                    \
      const char* vr1_ = (const char*)(VB) + (32 + ln31) * 128;             \
      short8 a00_ = *(const short8*)(vr0_ + (((SUB)*64      + hi*16) ^ rsw));\
      short8 a01_ = *(const short8*)(vr0_ + (((SUB)*64 + 32 + hi*16) ^ rsw));\
      short8 a10_ = *(const short8*)(vr1_ + (((SUB)*64      + hi*16) ^ rsw));\
      short8 a11_ = *(const short8*)(vr1_ + (((SUB)*64 + 32 + hi*16) ^ rsw));\
      acc0 = __builtin_amdgcn_mfma_f32_32x32x16_bf16(a00_, f0_.v, acc0, 0,0,0); \
      acc0 = __builtin_amdgcn_mfma_f32_32x32x16_bf16(a01_, f1_.v, acc0, 0,0,0); \
      acc1 = __builtin_amdgcn_mfma_f32_32x32x16_bf16(a10_, f0_.v, acc1, 0,0,0); \
      acc1 = __builtin_amdgcn_mfma_f32_32x32x16_bf16(a11_, f1_.v, acc1, 0,0,0); \
      accl = __builtin_amdgcn_mfma_f32_32x32x16_bf16(onesv, f0_.v, accl, 0,0,0);\
      accl = __builtin_amdgcn_mfma_f32_32x32x16_bf16(onesv, f1_.v, accl, 0,0,0);\
    }                                                                       \
  } while (0)

__global__ __launch_bounds__(256, 3)
void sattn_mid(const float* __restrict__ Qg, const float* __restrict__ Kg,
               const float* __restrict__ Vg, float* __restrict__ W)
{
  const int id = blockIdx.x;
  const int bh = id & 31;
  const int e  = id >> 5;
  const int g  = TG[e];
  const int t0 = TT0[e], t1 = TT1[e];
  float* rec = W + (size_t)(bh * NCHUNK + TREC[e]) * RECSZ;
  const int b = bh >> 3, h = bh & 7;

  const int tid  = threadIdx.x;
  const int wave = tid >> 6;
  const int lane = tid & 63;
  const int ln31 = lane & 31;
  const int hi   = lane >> 5;

  __shared__ __align__(16) struct { ushort kt[64 * 64]; ushort vt[64 * 64]; } lds;

  const int q0w = g * 128 + wave * 32;
  const int qi  = q0w + ln31;
  const int tw  = 4 * g + wave;
  const int rsw = (ln31 & 7) << 4;

  short8 qf[4];
  {
    const float* qp = Qg + (((size_t)b * NL + qi) * NH + h) * NE;
    #pragma unroll
    for (int st = 0; st < 4; ++st) {
      const float* qpe = qp + st * 16 + hi * 8;
      union { short8 v; uint32_t u[4]; } f;
      #pragma unroll
      for (int j = 0; j < 4; ++j)
        f.u[j] = pkbf(qpe[2 * j] * KS, qpe[2 * j + 1] * KS);
      qf[st] = f.v;
    }
  }
  short8 onesv;
  {
    union { short8 v; uint32_t u[4]; } o;
    #pragma unroll
    for (int j = 0; j < 4; ++j) o.u[j] = 0x3F803F80u;
    onesv = o.v;
  }

  f32x16 acc0, acc1, accl;
  #pragma unroll
  for (int i = 0; i < 16; ++i) { acc0[i] = 0.f; acc1[i] = 0.f; accl[i] = 0.f; }

  const int krow = tid >> 2,        kcol = (tid & 3) * 16;
  const int vk0  = (tid & 15) * 4,  vd0  = (tid >> 4) * 4;
  const int kbase = t0 * 32;
  const float* kpp = Kg + (((size_t)b * NL + kbase + krow) * NH + h) * NE + kcol;
  const float* vpp = Vg + (((size_t)b * NL + kbase + vk0 ) * NH + h) * ND + vd0;
  const int kswz  = (krow & 7) << 4;
  const int kcol2 = kcol * 2;

  float4 kx0, kx1, kx2, kx3, vx0, vx1, vx2, vx3;

  const int nr = (t1 - t0) >> 1;
  LD(0);
  STG((char*)lds.kt, (char*)lds.vt);
  __syncthreads();
  if (nr > 1) LD(1);
  for (int r = 0;;) {
    const int tt = t0 + 2 * r;
    if (tt     <= tw) COMPUTE(tt,     0, (char*)lds.kt, (char*)lds.vt);
    if (tt + 1 <= tw) COMPUTE(tt + 1, 1, (char*)lds.kt, (char*)lds.vt);
    if (++r == nr) break;
    __syncthreads();
    STG((char*)lds.kt, (char*)lds.vt);
    __syncthreads();
    if (r + 1 < nr) LD(r + 1);
  }

  #pragma unroll
  for (int r = 0; r < 16; ++r) {
    int d = (r & 3) + 8 * (r >> 2) + 4 * hi;
    rec[d * 128 + wave * 32 + ln31]        = acc0[r];
    rec[(32 + d) * 128 + wave * 32 + ln31] = acc1[r];
  }
  if (hi == 0) rec[8192 + wave * 32 + ln31] = accl[0];
}

__global__ __launch_bounds__(256)
void sattn_combine(const float* __restrict__ W, float* __restrict__ Og)
{
  const int id = blockIdx.x;
  const int h2 = id & 1, g = (id >> 1) & 15, bh = id >> 5;
  const int b = bh >> 3, h = bh & 7;
  const int tid = threadIdx.x;

  __shared__ float sd[64][67];
  __shared__ float Lq[64];

  const float* rec0 = W + (size_t)(bh * NCHUNK + CUMD[g]) * RECSZ;
  const int nc = NCHD[g];

  #pragma unroll
  for (int rep = 0; rep < 4; ++rep) {
    int d  = rep * 16 + (tid >> 4);
    int q4 = (tid & 15) * 4;
    float4 a = {0.f, 0.f, 0.f, 0.f};
    for (int c = 0; c < nc; ++c) {
      float4 v = *(const float4*)(rec0 + (size_t)c * RECSZ + d * 128 + h2 * 64 + q4);
      a.x += v.x; a.y += v.y; a.z += v.z; a.w += v.w;
    }
    sd[d][q4 + 0] = a.x; sd[d][q4 + 1] = a.y;
    sd[d][q4 + 2] = a.z; sd[d][q4 + 3] = a.w;
  }
  if (tid < 64) {
    float a = 0.f;
    for (int c = 0; c < nc; ++c) a += rec0[(size_t)c * RECSZ + 8192 + h2 * 64 + tid];
    Lq[tid] = 1.0f / a;
  }
  __syncthreads();
  #pragma unroll
  for (int rep = 0; rep < 4; ++rep) {
    int q  = rep * 16 + (tid >> 4);
    int d4 = (tid & 15) * 4;
    float l = Lq[q];
    float4 o = { sd[d4][q] * l, sd[d4 + 1][q] * l, sd[d4 + 2][q] * l, sd[d4 + 3][q] * l };
    *(float4*)(Og + (((size_t)b * NL + g * 128 + h2 * 64 + q) * NH + h) * ND + d4) = o;
  }
}

extern "C" void kernel_launch(void* const* d_in, const int* in_sizes, int n_in,
                              void* d_out, int out_size, void* d_ws, size_t ws_size,
                              hipStream_t stream) {
  const float* Q = (const float*)d_in[0];
  const float* K = (const float*)d_in[1];
  const float* V = (const float*)d_in[2];
  float* O = (float*)d_out;
  const size_t recbytes = (size_t)32 * NUNIT * RECSZ32 * sizeof(float);  // 42.6 MB
  const size_t imgsz    = (size_t)32 * 32 * 8192;                        // 8.39 MB each
  const size_t need_full = recbytes + 2 * imgsz;                         // 59.4 MB (== R8 proven)
  const size_t need_mid  = (size_t)32 * NCHUNK * RECSZ * sizeof(float);  // 42.6 MB
  float* W = (float*)d_ws;
  if (ws_size >= need_full) {
    char* kimg = (char*)d_ws + recbytes;
    char* vimg = kimg + imgsz;
    convkv        <<<dim3(1024), dim3(256), 0, stream>>>(K, V, kimg, vimg);
    sattn_wave    <<<dim3(1280), dim3(256), 0, stream>>>(Q, kimg, vimg, W);
    sattn_combine32<<<dim3(2048), dim3(256), 0, stream>>>(W, O);
  } else {
    sattn_mid     <<<dim3(32 * NCHUNK), dim3(256), 0, stream>>>(Q, K, V, W);
    sattn_combine <<<dim3(1024), dim3(256), 0, stream>>>(W, O);
  }
}

// Round 10
// 70.605 us; speedup vs baseline: 1.0365x; 1.0365x over previous
//
#include <hip/hip_runtime.h>
#include <hip/hip_bf16.h>
#include <stdint.h>

typedef __attribute__((ext_vector_type(8))) short short8;
typedef __attribute__((ext_vector_type(16))) float f32x16;

namespace {
constexpr int NB = 4, NL = 2048, NH = 8, NE = 64, ND = 64;
constexpr float KS = 0.125f * 1.44269504f;   // 1/sqrt(E)*log2(e): exp2-domain logits
constexpr int RECSZ32 = 2080;                // per-unit record: O^T 64*32 + l 32 (floats)
constexpr int NUNIT   = 160;                 // units per bh
constexpr int NCHUNK = 40;                   // fallback path constants
constexpr int RECSZ  = 8320;
constexpr int KSTEP  = 64 * NH * NE;
}

// Unit table: 40 blocks x 4 waves, entry = (k<<6)|s. Blocks 0..24 = {16,16,16,16}
// (64 tiles, launched first), 25..39 = {z,16-z,z,16-z} (32 tiles). Bijective over
// all (s,k) with s in [0,64), k <= s>>4.
__device__ const unsigned char TBL[160] = {
  15,16,17,18,  19,20,21,22,  23,24,25,26,  27,28,29,30,
  31,95,32,96,  33,97,34,98,  35,99,36,100, 37,101,38,102,
  39,103,40,104, 41,105,42,106, 43,107,44,108, 45,109,46,110,
  47,111,175,48, 112,176,49,113, 177,50,114,178, 51,115,179,52,
  116,180,53,117, 181,54,118,182, 55,119,183,56, 120,184,57,121,
  185,58,122,186, 59,123,187,60, 124,188,61,125, 189,62,126,190,
  63,127,191,255,
  0,94,160,254,  1,93,161,253,  2,92,162,252,  3,91,163,251,
  4,90,164,250,  5,89,165,249,  6,88,166,248,  7,87,167,247,
  8,86,168,246,  9,85,169,245, 10,84,170,244, 11,83,171,243,
  12,82,172,242, 13,81,173,241, 14,80,174,240};

// -------- fallback chunk tables (R6 path) --------
__device__ const unsigned char TG[40] = {
  3,7,7,10,11,11,11,14,14,15,15,15,15,
  6,6,9,9,10,10,12,12,13,13,13,13,14,14,
  2,5,5,8,8,8,9,12,12,
  4,4,1,0};
__device__ const unsigned char TT0[40] = {
  0,0,16,0,0,16,32,0,16,0,16,32,48,
  0,14,0,14,16,30,0,14,0,14,28,42,32,46,
  0,0,12,0,12,24,28,28,40,
  0,10,0,0};
__device__ const unsigned char TT1[40] = {
  16,16,32,16,16,32,48,16,32,16,32,48,64,
  14,28,14,28,30,44,14,28,14,28,42,56,46,60,
  12,12,24,12,24,36,40,40,52,
  10,20,8,4};
__device__ const unsigned char TREC[40] = {
  3,10,11,18,21,22,23,32,33,36,37,38,39,
  8,9,15,16,19,20,24,25,28,29,30,31,34,35,
  2,6,7,12,13,14,17,26,27,
  4,5,1,0};
__device__ const unsigned char CUMD[16] = {0,1,2,3,4,6,8,10,12,15,18,21,24,28,32,36};
__device__ const unsigned char NCHD[16] = {1,1,1,1,2,2,2,2,3,3,3,3,4,4,4,4};

__device__ __forceinline__ ushort bfb(float x) {
  __hip_bfloat16 b(x);
  return __builtin_bit_cast(ushort, b);
}
__device__ __forceinline__ uint32_t pkbf(float lo, float hi) {
  return (uint32_t)bfb(lo) | ((uint32_t)bfb(hi) << 16);
}

// ==== fragment-linear images ====
// K: per bh (256KB): tile t (32 keys), frag st in [0,4): 1KB, lane l holds 16B =
//    K[key = t*32 + (l&31)][e = st*16 + (l>>5)*8 .. +8] bf16.
// V: per bh: tile t, frag f in [0,4): lane l holds 16B =
//    V^T[d = (f>>1)*32 + (l&31)][keys t*32 + (f&1)*16 + (l>>5)*8 .. +8] bf16.

// -------- convert: build fragment-linear bf16 images (one-shot) --------
__global__ __launch_bounds__(256)
void convfrag(const float* __restrict__ Kg, const float* __restrict__ Vg,
              char* __restrict__ kimg, char* __restrict__ vimg)
{
  const int id = blockIdx.x;          // 1024 = 32 bh * 32 rounds (64 keys each)
  const int kr = id & 31, bh = id >> 5;
  const int b = bh >> 3, h = bh & 7;
  const int tid = threadIdx.x;

  __shared__ __align__(16) char  kt[64 * 128];   // bf16, swizzled rows
  __shared__ __align__(16) float vt[64 * 64];    // fp32, linear [key][d]

  const int key = tid >> 2;
  const int e0  = (tid & 3) * 16;
  { // K rows -> bf16 swizzled LDS
    const float* kp = Kg + (((size_t)b * NL + kr * 64 + key) * NH + h) * NE + e0;
    float4 a = *(const float4*)kp,       c = *(const float4*)(kp + 4);
    float4 d2 = *(const float4*)(kp + 8), f = *(const float4*)(kp + 12);
    uint4 wA = { pkbf(a.x,a.y), pkbf(a.z,a.w), pkbf(c.x,c.y), pkbf(c.z,c.w) };
    uint4 wB = { pkbf(d2.x,d2.y), pkbf(d2.z,d2.w), pkbf(f.x,f.y), pkbf(f.z,f.w) };
    const int sw = (key & 7) << 4;
    *(uint4*)(kt + key * 128 + ((2 * e0)      ^ sw)) = wA;
    *(uint4*)(kt + key * 128 + ((2 * e0 + 16) ^ sw)) = wB;
  }
  { // V rows -> fp32 linear LDS
    const float* vp = Vg + (((size_t)b * NL + kr * 64 + key) * NH + h) * ND + e0;
    float* dst = vt + key * 64 + e0;
    *(float4*)(dst)      = *(const float4*)(vp);
    *(float4*)(dst + 4)  = *(const float4*)(vp + 4);
    *(float4*)(dst + 8)  = *(const float4*)(vp + 8);
    *(float4*)(dst + 12) = *(const float4*)(vp + 12);
  }
  __syncthreads();

  char* kob = kimg + (size_t)bh * 262144 + (size_t)kr * 2 * 4096;
  char* vob = vimg + (size_t)bh * 262144 + (size_t)kr * 2 * 4096;
  #pragma unroll
  for (int it = 0; it < 2; ++it) {     // K fragments: 512 x 16B
    int lin = it * 256 + tid;
    int fi = lin >> 6, l = lin & 63;
    int tt = fi >> 2, st = fi & 3;
    int ky = tt * 32 + (l & 31);
    int e  = st * 16 + (l >> 5) * 8;
    uint4 w = *(const uint4*)(kt + ky * 128 + ((2 * e) ^ ((ky & 7) << 4)));
    *(uint4*)(kob + tt * 4096 + st * 1024 + l * 16) = w;
  }
  #pragma unroll
  for (int it = 0; it < 2; ++it) {     // V fragments: 512 x 16B
    int lin = it * 256 + tid;
    int fi = lin >> 6, l = lin & 63;
    int tt = fi >> 2, f = fi & 3;
    int d  = (f >> 1) * 32 + (l & 31);
    int k0 = tt * 32 + (f & 1) * 16 + (l >> 5) * 8;
    const float* c0 = vt + k0 * 64 + d;
    uint4 w = { pkbf(c0[0],   c0[64]),  pkbf(c0[128], c0[192]),
                pkbf(c0[256], c0[320]), pkbf(c0[384], c0[448]) };
    *(uint4*)(vob + tt * 4096 + f * 1024 + l * 16) = w;
  }
}

// -------- main: wave-autonomous, barrier-free, LDS-free, COALESCED frag reads --------
__global__ __launch_bounds__(256)
void sattn_frag(const float* __restrict__ Qg, const char* __restrict__ kimg,
                const char* __restrict__ vimg, float* __restrict__ W)
{
  const int id   = blockIdx.x;        // 1280 = 32 bh * 40 ublk ; id%8 = bh%8 -> XCD pin
  const int bh   = id & 31;
  const int ublk = id >> 5;
  const int b = bh >> 3, h = bh & 7;

  const int tid  = threadIdx.x;
  const int wave = tid >> 6;
  const int lane = tid & 63;
  const int ln31 = lane & 31;
  const int hi   = lane >> 5;

  const int e   = TBL[ublk * 4 + wave];
  const int s   = e & 63, k = e >> 6;
  const int t0u = k * 16;
  const int t1u = (t0u + 16 < s + 1) ? t0u + 16 : s + 1;
  const int G   = s >> 4;
  const int rix = 8 * G * (G + 1) + (s & 15) * (G + 1) + k;
  float* rec = W + ((size_t)bh * NUNIT + rix) * RECSZ32;

  const int q0w = s * 32;
  const int qi  = q0w + ln31;
  const char* kb_img = kimg + (size_t)bh * 262144 + lane * 16;
  const char* vb_img = vimg + (size_t)bh * 262144 + lane * 16;

  // Q fragments, pre-scaled by KS
  short8 qf[4];
  {
    const float* qp = Qg + (((size_t)b * NL + qi) * NH + h) * NE;
    #pragma unroll
    for (int st = 0; st < 4; ++st) {
      const float* qpe = qp + st * 16 + hi * 8;
      union { short8 v; uint32_t u[4]; } f;
      #pragma unroll
      for (int j = 0; j < 4; ++j)
        f.u[j] = pkbf(qpe[2 * j] * KS, qpe[2 * j + 1] * KS);
      qf[st] = f.v;
    }
  }

  f32x16 acc0, acc1;
  #pragma unroll
  for (int i = 0; i < 16; ++i) { acc0[i] = 0.f; acc1[i] = 0.f; }
  float ls = 0.f;

  for (int t = t0u; t < t1u; ++t) {
    const char* kp = kb_img + (size_t)t * 4096;
    const char* vp = vb_img + (size_t)t * 4096;
    // 8 coalesced dwordx4 loads (all independent; no barriers anywhere)
    short8 a00 = *(const short8*)(vp);
    short8 a01 = *(const short8*)(vp + 1024);
    short8 a10 = *(const short8*)(vp + 2048);
    short8 a11 = *(const short8*)(vp + 3072);
    short8 kf0 = *(const short8*)(kp);
    short8 kf1 = *(const short8*)(kp + 1024);
    short8 kf2 = *(const short8*)(kp + 2048);
    short8 kf3 = *(const short8*)(kp + 3072);

    // S^T = K · (KS*Q)^T
    f32x16 sv;
    #pragma unroll
    for (int i = 0; i < 16; ++i) sv[i] = 0.f;
    sv = __builtin_amdgcn_mfma_f32_32x32x16_bf16(kf0, qf[0], sv, 0, 0, 0);
    sv = __builtin_amdgcn_mfma_f32_32x32x16_bf16(kf1, qf[1], sv, 0, 0, 0);
    sv = __builtin_amdgcn_mfma_f32_32x32x16_bf16(kf2, qf[2], sv, 0, 0, 0);
    sv = __builtin_amdgcn_mfma_f32_32x32x16_bf16(kf3, qf[3], sv, 0, 0, 0);

    // masks + P = exp2(logit), fixed max m=0
    const int kv0 = t * 32;
    const int delta = q0w - kv0;
    const int qrelh = (qi - kv0) - 4 * hi;
    float ps0 = 0.f, ps1 = 0.f;
    if (t == s) {             // diagonal: causal + pow2
      #pragma unroll
      for (int r = 0; r < 16; ++r) {
        const int cr = (r & 3) + 8 * (r >> 2);
        int diff = qrelh - cr;
        float lg = sv[r];
        bool p2 = (diff > 1) & ((diff & (diff - 1)) == 0);
        lg = p2 ? 0.f : lg;
        lg = (diff < 0) ? -__builtin_inff() : lg;
        float p = exp2f(lg);
        sv[r] = p; (r & 1 ? ps1 : ps0) += p;
      }
    } else {
      int pmax = 1 << (31 - __clz(delta + 31));
      if (pmax >= delta - 31) {    // pow2 stride window intersects tile
        #pragma unroll
        for (int r = 0; r < 16; ++r) {
          const int cr = (r & 3) + 8 * (r >> 2);
          int diff = qrelh - cr;
          bool p2 = (diff > 1) & ((diff & (diff - 1)) == 0);
          float p = exp2f(p2 ? 0.f : sv[r]);
          sv[r] = p; (r & 1 ? ps1 : ps0) += p;
        }
      } else {                     // clean: bare exp2
        #pragma unroll
        for (int r = 0; r < 16; ++r) {
          float p = exp2f(sv[r]);
          sv[r] = p; (r & 1 ? ps1 : ps0) += p;
        }
      }
    }
    ls += ps0 + ps1;

    // pack P -> bf16 fragments (4 shfls)
    uint32_t w0 = pkbf(sv[0],  sv[1]),  w1 = pkbf(sv[2],  sv[3]);
    uint32_t w2 = pkbf(sv[4],  sv[5]),  w3 = pkbf(sv[6],  sv[7]);
    uint32_t w4 = pkbf(sv[8],  sv[9]),  w5 = pkbf(sv[10], sv[11]);
    uint32_t w6 = pkbf(sv[12], sv[13]), w7 = pkbf(sv[14], sv[15]);
    uint32_t y0 = __shfl_xor(hi ? w0 : w2, 32);
    uint32_t y1 = __shfl_xor(hi ? w1 : w3, 32);
    uint32_t y2 = __shfl_xor(hi ? w4 : w6, 32);
    uint32_t y3 = __shfl_xor(hi ? w5 : w7, 32);
    union { short8 v; uint32_t u[4]; } f0, f1;
    if (hi == 0) {
      f0.u[0] = w0; f0.u[1] = w1; f0.u[2] = y0; f0.u[3] = y1;   // keys 0..15
      f1.u[0] = w4; f1.u[1] = w5; f1.u[2] = y2; f1.u[3] = y3;   // keys 16..31
    } else {
      f0.u[0] = y0; f0.u[1] = y1; f0.u[2] = w2; f0.u[3] = w3;
      f1.u[0] = y2; f1.u[1] = y3; f1.u[2] = w6; f1.u[3] = w7;
    }

    // O^T += V^T . P^T
    acc0 = __builtin_amdgcn_mfma_f32_32x32x16_bf16(a00, f0.v, acc0, 0, 0, 0);
    acc0 = __builtin_amdgcn_mfma_f32_32x32x16_bf16(a01, f1.v, acc0, 0, 0, 0);
    acc1 = __builtin_amdgcn_mfma_f32_32x32x16_bf16(a10, f0.v, acc1, 0, 0, 0);
    acc1 = __builtin_amdgcn_mfma_f32_32x32x16_bf16(a11, f1.v, acc1, 0, 0, 0);
  }

  // epilogue: unnormalized O^T partial + l
  ls += __shfl_xor(ls, 32);
  #pragma unroll
  for (int r = 0; r < 16; ++r) {
    int d = (r & 3) + 8 * (r >> 2) + 4 * hi;
    rec[d * 32 + ln31]        = acc0[r];
    rec[(32 + d) * 32 + ln31] = acc1[r];
  }
  if (hi == 0) rec[2048 + ln31] = ls;
}

// -------- combine: per (bh, strip): sum <=4 unit records, normalize, transpose --------
__global__ __launch_bounds__(256)
void sattn_combine32(const float* __restrict__ W, float* __restrict__ Og)
{
  const int id = blockIdx.x;             // 2048 = 32 bh * 64 strips
  const int s  = id & 63, bh = id >> 6;
  const int b = bh >> 3, h = bh & 7;
  const int tid = threadIdx.x;

  const int G = s >> 4, i = s & 15;
  const int cum = 8 * G * (G + 1) + i * (G + 1);
  const int nc  = G + 1;
  const float* rec0 = W + ((size_t)bh * NUNIT + cum) * RECSZ32;

  __shared__ float sd[64][33];
  __shared__ float Lq[32];

  {
    int d = tid >> 2, q4 = (tid & 3) * 8;
    float4 a0 = {0,0,0,0}, a1 = {0,0,0,0};
    for (int c = 0; c < nc; ++c) {
      const float* rp = rec0 + (size_t)c * RECSZ32 + d * 32 + q4;
      float4 v0 = *(const float4*)rp, v1 = *(const float4*)(rp + 4);
      a0.x += v0.x; a0.y += v0.y; a0.z += v0.z; a0.w += v0.w;
      a1.x += v1.x; a1.y += v1.y; a1.z += v1.z; a1.w += v1.w;
    }
    sd[d][q4+0] = a0.x; sd[d][q4+1] = a0.y; sd[d][q4+2] = a0.z; sd[d][q4+3] = a0.w;
    sd[d][q4+4] = a1.x; sd[d][q4+5] = a1.y; sd[d][q4+6] = a1.z; sd[d][q4+7] = a1.w;
  }
  if (tid < 32) {
    float a = 0.f;
    for (int c = 0; c < nc; ++c) a += rec0[(size_t)c * RECSZ32 + 2048 + tid];
    Lq[tid] = 1.0f / a;
  }
  __syncthreads();
  {
    int q = tid >> 3, d8 = (tid & 7) * 8;
    float l = Lq[q];
    float4 o0 = { sd[d8+0][q]*l, sd[d8+1][q]*l, sd[d8+2][q]*l, sd[d8+3][q]*l };
    float4 o1 = { sd[d8+4][q]*l, sd[d8+5][q]*l, sd[d8+6][q]*l, sd[d8+7][q]*l };
    float* op = Og + (((size_t)b * NL + s * 32 + q) * NH + h) * ND + d8;
    *(float4*)op = o0; *(float4*)(op + 4) = o1;
  }
}

// ======== fallback path (R6-proven register-staged; used only if ws too small) ========
#define LD(RR) do {                                                         \
    const float* kp_ = kpp + (size_t)(RR) * KSTEP;                          \
    const float* vp_ = vpp + (size_t)(RR) * KSTEP;                          \
    kx0 = *(const float4*)(kp_);      kx1 = *(const float4*)(kp_ + 4);      \
    kx2 = *(const float4*)(kp_ + 8);  kx3 = *(const float4*)(kp_ + 12);     \
    vx0 = *(const float4*)(vp_);               vx1 = *(const float4*)(vp_ + NH*ND); \
    vx2 = *(const float4*)(vp_ + 2*NH*ND);     vx3 = *(const float4*)(vp_ + 3*NH*ND); \
  } while (0)

#define STG(KB, VB) do {                                                    \
    uint4 kwA = { pkbf(kx0.x,kx0.y), pkbf(kx0.z,kx0.w),                     \
                  pkbf(kx1.x,kx1.y), pkbf(kx1.z,kx1.w) };                   \
    uint4 kwB = { pkbf(kx2.x,kx2.y), pkbf(kx2.z,kx2.w),                     \
                  pkbf(kx3.x,kx3.y), pkbf(kx3.z,kx3.w) };                   \
    *(uint4*)((KB) + krow*128 + ( kcol2        ^ kswz)) = kwA;              \
    *(uint4*)((KB) + krow*128 + ((kcol2 + 16)  ^ kswz)) = kwB;              \
    _Pragma("unroll")                                                       \
    for (int j_ = 0; j_ < 4; ++j_) {                                        \
      int d_ = vd0 + j_;                                                    \
      char* vr_ = (VB) + d_*128;                                            \
      int vs_ = (d_ & 7) << 4;                                              \
      *(uint32_t*)(vr_ + ((vk0*2    ) ^ vs_)) = pkbf(vx0[j_], vx1[j_]);     \
      *(uint32_t*)(vr_ + ((vk0*2 + 4) ^ vs_)) = pkbf(vx2[j_], vx3[j_]);     \
    }                                                                       \
  } while (0)

#define COMPUTE(TT, SUB, KB, VB) do {                                       \
    const int kv0_ = (TT) * 32;                                             \
    f32x16 s;                                                               \
    _Pragma("unroll")                                                       \
    for (int i_ = 0; i_ < 16; ++i_) s[i_] = 0.f;                            \
    { const char* kb_ = (const char*)(KB) + ((SUB)*32 + ln31) * 128;        \
      _Pragma("unroll")                                                     \
      for (int st_ = 0; st_ < 4; ++st_) {                                   \
        short8 kf_ = *(const short8*)(kb_ + ((st_*32 + hi*16) ^ rsw));      \
        s = __builtin_amdgcn_mfma_f32_32x32x16_bf16(kf_, qf[st_], s, 0,0,0);\
      } }                                                                   \
    const int delta_ = q0w - kv0_;                                          \
    const int qrelh_ = (qi - kv0_) - 4 * hi;                                \
    if ((TT) == tw) {                                                       \
      _Pragma("unroll")                                                     \
      for (int r_ = 0; r_ < 16; ++r_) {                                     \
        const int cr_ = (r_ & 3) + 8 * (r_ >> 2);                           \
        int diff_ = qrelh_ - cr_;                                           \
        float lg_ = s[r_];                                                  \
        bool p2_ = (diff_ > 1) & ((diff_ & (diff_ - 1)) == 0);              \
        lg_ = p2_ ? 0.f : lg_;                                              \
        lg_ = (diff_ < 0) ? -__builtin_inff() : lg_;                        \
        s[r_] = exp2f(lg_);                                                 \
      }                                                                     \
    } else {                                                                \
      int pmax_ = 1 << (31 - __clz(delta_ + 31));                           \
      if (pmax_ >= delta_ - 31) {                                           \
        _Pragma("unroll")                                                   \
        for (int r_ = 0; r_ < 16; ++r_) {                                   \
          const int cr_ = (r_ & 3) + 8 * (r_ >> 2);                         \
          int diff_ = qrelh_ - cr_;                                         \
          bool p2_ = (diff_ > 1) & ((diff_ & (diff_ - 1)) == 0);            \
          s[r_] = exp2f(p2_ ? 0.f : s[r_]);                                 \
        }                                                                   \
      } else {                                                              \
        _Pragma("unroll")                                                   \
        for (int r_ = 0; r_ < 16; ++r_) s[r_] = exp2f(s[r_]);               \
      }                                                                     \
    }                                                                       \
    uint32_t w0_ = pkbf(s[0],  s[1]),  w1_ = pkbf(s[2],  s[3]);             \
    uint32_t w2_ = pkbf(s[4],  s[5]),  w3_ = pkbf(s[6],  s[7]);             \
    uint32_t w4_ = pkbf(s[8],  s[9]),  w5_ = pkbf(s[10], s[11]);            \
    uint32_t w6_ = pkbf(s[12], s[13]), w7_ = pkbf(s[14], s[15]);            \
    uint32_t y0_ = __shfl_xor(hi ? w0_ : w2_, 32);                          \
    uint32_t y1_ = __shfl_xor(hi ? w1_ : w3_, 32);                          \
    uint32_t y2_ = __shfl_xor(hi ? w4_ : w6_, 32);                          \
    uint32_t y3_ = __shfl_xor(hi ? w5_ : w7_, 32);                          \
    union { short8 v; uint32_t u[4]; } f0_, f1_;                            \
    if (hi == 0) {                                                          \
      f0_.u[0] = w0_; f0_.u[1] = w1_; f0_.u[2] = y0_; f0_.u[3] = y1_;       \
      f1_.u[0] = w4_; f1_.u[1] = w5_; f1_.u[2] = y2_; f1_.u[3] = y3_;       \
    } else {                                                                \
      f0_.u[0] = y0_; f0_.u[1] = y1_; f0_.u[2] = w2_; f0_.u[3] = w3_;       \
      f1_.u[0] = y2_; f1_.u[1] = y3_; f1_.u[2] = w6_; f1_.u[3] = w7_;       \
    }                                                                       \
    { const char* vr0_ = (const char*)(VB) + ln31 * 128;                    \
      const char* vr1_ = (const char*)(VB) + (32 + ln31) * 128;             \
      short8 a00_ = *(const short8*)(vr0_ + (((SUB)*64      + hi*16) ^ rsw));\
      short8 a01_ = *(const short8*)(vr0_ + (((SUB)*64 + 32 + hi*16) ^ rsw));\
      short8 a10_ = *(const short8*)(vr1_ + (((SUB)*64      + hi*16) ^ rsw));\
      short8 a11_ = *(const short8*)(vr1_ + (((SUB)*64 + 32 + hi*16) ^ rsw));\
      acc0 = __builtin_amdgcn_mfma_f32_32x32x16_bf16(a00_, f0_.v, acc0, 0,0,0); \
      acc0 = __builtin_amdgcn_mfma_f32_32x32x16_bf16(a01_, f1_.v, acc0, 0,0,0); \
      acc1 = __builtin_amdgcn_mfma_f32_32x32x16_bf16(a10_, f0_.v, acc1, 0,0,0); \
      acc1 = __builtin_amdgcn_mfma_f32_32x32x16_bf16(a11_, f1_.v, acc1, 0,0,0); \
      accl = __builtin_amdgcn_mfma_f32_32x32x16_bf16(onesv, f0_.v, accl, 0,0,0);\
      accl = __builtin_amdgcn_mfma_f32_32x32x16_bf16(onesv, f1_.v, accl, 0,0,0);\
    }                                                                       \
  } while (0)

__global__ __launch_bounds__(256, 3)
void sattn_mid(const float* __restrict__ Qg, const float* __restrict__ Kg,
               const float* __restrict__ Vg, float* __restrict__ W)
{
  const int id = blockIdx.x;
  const int bh = id & 31;
  const int e  = id >> 5;
  const int g  = TG[e];
  const int t0 = TT0[e], t1 = TT1[e];
  float* rec = W + (size_t)(bh * NCHUNK + TREC[e]) * RECSZ;
  const int b = bh >> 3, h = bh & 7;

  const int tid  = threadIdx.x;
  const int wave = tid >> 6;
  const int lane = tid & 63;
  const int ln31 = lane & 31;
  const int hi   = lane >> 5;

  __shared__ __align__(16) struct { ushort kt[64 * 64]; ushort vt[64 * 64]; } lds;

  const int q0w = g * 128 + wave * 32;
  const int qi  = q0w + ln31;
  const int tw  = 4 * g + wave;
  const int rsw = (ln31 & 7) << 4;

  short8 qf[4];
  {
    const float* qp = Qg + (((size_t)b * NL + qi) * NH + h) * NE;
    #pragma unroll
    for (int st = 0; st < 4; ++st) {
      const float* qpe = qp + st * 16 + hi * 8;
      union { short8 v; uint32_t u[4]; } f;
      #pragma unroll
      for (int j = 0; j < 4; ++j)
        f.u[j] = pkbf(qpe[2 * j] * KS, qpe[2 * j + 1] * KS);
      qf[st] = f.v;
    }
  }
  short8 onesv;
  {
    union { short8 v; uint32_t u[4]; } o;
    #pragma unroll
    for (int j = 0; j < 4; ++j) o.u[j] = 0x3F803F80u;
    onesv = o.v;
  }

  f32x16 acc0, acc1, accl;
  #pragma unroll
  for (int i = 0; i < 16; ++i) { acc0[i] = 0.f; acc1[i] = 0.f; accl[i] = 0.f; }

  const int krow = tid >> 2,        kcol = (tid & 3) * 16;
  const int vk0  = (tid & 15) * 4,  vd0  = (tid >> 4) * 4;
  const int kbase = t0 * 32;
  const float* kpp = Kg + (((size_t)b * NL + kbase + krow) * NH + h) * NE + kcol;
  const float* vpp = Vg + (((size_t)b * NL + kbase + vk0 ) * NH + h) * ND + vd0;
  const int kswz  = (krow & 7) << 4;
  const int kcol2 = kcol * 2;

  float4 kx0, kx1, kx2, kx3, vx0, vx1, vx2, vx3;

  const int nr = (t1 - t0) >> 1;
  LD(0);
  STG((char*)lds.kt, (char*)lds.vt);
  __syncthreads();
  if (nr > 1) LD(1);
  for (int r = 0;;) {
    const int tt = t0 + 2 * r;
    if (tt     <= tw) COMPUTE(tt,     0, (char*)lds.kt, (char*)lds.vt);
    if (tt + 1 <= tw) COMPUTE(tt + 1, 1, (char*)lds.kt, (char*)lds.vt);
    if (++r == nr) break;
    __syncthreads();
    STG((char*)lds.kt, (char*)lds.vt);
    __syncthreads();
    if (r + 1 < nr) LD(r + 1);
  }

  #pragma unroll
  for (int r = 0; r < 16; ++r) {
    int d = (r & 3) + 8 * (r >> 2) + 4 * hi;
    rec[d * 128 + wave * 32 + ln31]        = acc0[r];
    rec[(32 + d) * 128 + wave * 32 + ln31] = acc1[r];
  }
  if (hi == 0) rec[8192 + wave * 32 + ln31] = accl[0];
}

__global__ __launch_bounds__(256)
void sattn_combine(const float* __restrict__ W, float* __restrict__ Og)
{
  const int id = blockIdx.x;
  const int h2 = id & 1, g = (id >> 1) & 15, bh = id >> 5;
  const int b = bh >> 3, h = bh & 7;
  const int tid = threadIdx.x;

  __shared__ float sd[64][67];
  __shared__ float Lq[64];

  const float* rec0 = W + (size_t)(bh * NCHUNK + CUMD[g]) * RECSZ;
  const int nc = NCHD[g];

  #pragma unroll
  for (int rep = 0; rep < 4; ++rep) {
    int d  = rep * 16 + (tid >> 4);
    int q4 = (tid & 15) * 4;
    float4 a = {0.f, 0.f, 0.f, 0.f};
    for (int c = 0; c < nc; ++c) {
      float4 v = *(const float4*)(rec0 + (size_t)c * RECSZ + d * 128 + h2 * 64 + q4);
      a.x += v.x; a.y += v.y; a.z += v.z; a.w += v.w;
    }
    sd[d][q4 + 0] = a.x; sd[d][q4 + 1] = a.y;
    sd[d][q4 + 2] = a.z; sd[d][q4 + 3] = a.w;
  }
  if (tid < 64) {
    float a = 0.f;
    for (int c = 0; c < nc; ++c) a += rec0[(size_t)c * RECSZ + 8192 + h2 * 64 + tid];
    Lq[tid] = 1.0f / a;
  }
  __syncthreads();
  #pragma unroll
  for (int rep = 0; rep < 4; ++rep) {
    int q  = rep * 16 + (tid >> 4);
    int d4 = (tid & 15) * 4;
    float l = Lq[q];
    float4 o = { sd[d4][q] * l, sd[d4 + 1][q] * l, sd[d4 + 2][q] * l, sd[d4 + 3][q] * l };
    *(float4*)(Og + (((size_t)b * NL + g * 128 + h2 * 64 + q) * NH + h) * ND + d4) = o;
  }
}

extern "C" void kernel_launch(void* const* d_in, const int* in_sizes, int n_in,
                              void* d_out, int out_size, void* d_ws, size_t ws_size,
                              hipStream_t stream) {
  const float* Q = (const float*)d_in[0];
  const float* K = (const float*)d_in[1];
  const float* V = (const float*)d_in[2];
  float* O = (float*)d_out;
  const size_t recbytes = (size_t)32 * NUNIT * RECSZ32 * sizeof(float);  // 42.6 MB
  const size_t imgsz    = (size_t)32 * 64 * 4096;                        // 8.39 MB each
  const size_t need_full = recbytes + 2 * imgsz;                         // 59.4 MB (proven)
  float* W = (float*)d_ws;
  if (ws_size >= need_full) {
    char* kimg = (char*)d_ws + recbytes;
    char* vimg = kimg + imgsz;
    convfrag       <<<dim3(1024), dim3(256), 0, stream>>>(K, V, kimg, vimg);
    sattn_frag     <<<dim3(1280), dim3(256), 0, stream>>>(Q, kimg, vimg, W);
    sattn_combine32<<<dim3(2048), dim3(256), 0, stream>>>(W, O);
  } else {
    sattn_mid      <<<dim3(32 * NCHUNK), dim3(256), 0, stream>>>(Q, K, V, W);
    sattn_combine  <<<dim3(1024), dim3(256), 0, stream>>>(W, O);
  }
}

// Round 11
// 66.932 us; speedup vs baseline: 1.0934x; 1.0549x over previous
//
#include <hip/hip_runtime.h>
#include <hip/hip_bf16.h>
#include <stdint.h>

typedef __attribute__((ext_vector_type(8))) short short8;
typedef __attribute__((ext_vector_type(16))) float f32x16;

namespace {
constexpr int NB = 4, NL = 2048, NH = 8, NE = 64, ND = 64;
constexpr float KS = 0.125f * 1.44269504f;   // 1/sqrt(E)*log2(e): exp2-domain logits
constexpr int RECSZ32 = 2080;                // per-unit record: O^T 64*32 + l 32 (floats)
constexpr int NUNIT   = 160;                 // units per bh
constexpr int NCHUNK = 40;                   // fallback path constants
constexpr int RECSZ  = 8320;
constexpr int KSTEP  = 64 * NH * NE;
}

// Unit order table, LPT (descending tile count). entry = (k<<6)|s, unit (s,k)
// covers tiles [16k, min(16k+16, s+1)). 100 full 16-tile units first, then
// partial units of size 15..1 (4 each). Consumed two-per-block (2-wave blocks).
__device__ const unsigned char ORD[160] = {
  63,127,191,255,
  48,112,176, 49,113,177, 50,114,178, 51,115,179, 52,116,180,
  53,117,181, 54,118,182, 55,119,183, 56,120,184, 57,121,185,
  58,122,186, 59,123,187, 60,124,188, 61,125,189, 62,126,190,
  47,111,175,
  32,96, 33,97, 34,98, 35,99, 36,100, 37,101, 38,102, 39,103,
  40,104, 41,105, 42,106, 43,107, 44,108, 45,109, 46,110,
  31,95,
  15,16,17,18,19,20,21,22,23,24,25,26,27,28,29,30,
  14,94,174,254, 13,93,173,253, 12,92,172,252, 11,91,171,251,
  10,90,170,250,  9,89,169,249,  8,88,168,248,  7,87,167,247,
   6,86,166,246,  5,85,165,245,  4,84,164,244,  3,83,163,243,
   2,82,162,242,  1,81,161,241,  0,80,160,240};

// -------- fallback chunk tables (R6 path) --------
__device__ const unsigned char TG[40] = {
  3,7,7,10,11,11,11,14,14,15,15,15,15,
  6,6,9,9,10,10,12,12,13,13,13,13,14,14,
  2,5,5,8,8,8,9,12,12,
  4,4,1,0};
__device__ const unsigned char TT0[40] = {
  0,0,16,0,0,16,32,0,16,0,16,32,48,
  0,14,0,14,16,30,0,14,0,14,28,42,32,46,
  0,0,12,0,12,24,28,28,40,
  0,10,0,0};
__device__ const unsigned char TT1[40] = {
  16,16,32,16,16,32,48,16,32,16,32,48,64,
  14,28,14,28,30,44,14,28,14,28,42,56,46,60,
  12,12,24,12,24,36,40,40,52,
  10,20,8,4};
__device__ const unsigned char TREC[40] = {
  3,10,11,18,21,22,23,32,33,36,37,38,39,
  8,9,15,16,19,20,24,25,28,29,30,31,34,35,
  2,6,7,12,13,14,17,26,27,
  4,5,1,0};
__device__ const unsigned char CUMD[16] = {0,1,2,3,4,6,8,10,12,15,18,21,24,28,32,36};
__device__ const unsigned char NCHD[16] = {1,1,1,1,2,2,2,2,3,3,3,3,4,4,4,4};

__device__ __forceinline__ ushort bfb(float x) {
  __hip_bfloat16 b(x);
  return __builtin_bit_cast(ushort, b);
}
__device__ __forceinline__ uint32_t pkbf(float lo, float hi) {
  return (uint32_t)bfb(lo) | ((uint32_t)bfb(hi) << 16);
}

// ==== fragment-linear images ====
// K: per bh (256KB): tile t (32 keys), frag st in [0,4): 1KB, lane l holds 16B =
//    K[key = t*32 + (l&31)][e = st*16 + (l>>5)*8 .. +8] bf16.
// V: per bh: tile t, frag f in [0,4): lane l holds 16B =
//    V^T[d = (f>>1)*32 + (l&31)][keys t*32 + (f&1)*16 + (l>>5)*8 .. +8] bf16.

// -------- convert: build fragment-linear bf16 images (one-shot; R10-proven) --------
__global__ __launch_bounds__(256)
void convfrag(const float* __restrict__ Kg, const float* __restrict__ Vg,
              char* __restrict__ kimg, char* __restrict__ vimg)
{
  const int id = blockIdx.x;          // 1024 = 32 bh * 32 rounds (64 keys each)
  const int kr = id & 31, bh = id >> 5;
  const int b = bh >> 3, h = bh & 7;
  const int tid = threadIdx.x;

  __shared__ __align__(16) char  kt[64 * 128];   // bf16, swizzled rows
  __shared__ __align__(16) float vt[64 * 64];    // fp32, linear [key][d]

  const int key = tid >> 2;
  const int e0  = (tid & 3) * 16;
  { // K rows -> bf16 swizzled LDS
    const float* kp = Kg + (((size_t)b * NL + kr * 64 + key) * NH + h) * NE + e0;
    float4 a = *(const float4*)kp,       c = *(const float4*)(kp + 4);
    float4 d2 = *(const float4*)(kp + 8), f = *(const float4*)(kp + 12);
    uint4 wA = { pkbf(a.x,a.y), pkbf(a.z,a.w), pkbf(c.x,c.y), pkbf(c.z,c.w) };
    uint4 wB = { pkbf(d2.x,d2.y), pkbf(d2.z,d2.w), pkbf(f.x,f.y), pkbf(f.z,f.w) };
    const int sw = (key & 7) << 4;
    *(uint4*)(kt + key * 128 + ((2 * e0)      ^ sw)) = wA;
    *(uint4*)(kt + key * 128 + ((2 * e0 + 16) ^ sw)) = wB;
  }
  { // V rows -> fp32 linear LDS
    const float* vp = Vg + (((size_t)b * NL + kr * 64 + key) * NH + h) * ND + e0;
    float* dst = vt + key * 64 + e0;
    *(float4*)(dst)      = *(const float4*)(vp);
    *(float4*)(dst + 4)  = *(const float4*)(vp + 4);
    *(float4*)(dst + 8)  = *(const float4*)(vp + 8);
    *(float4*)(dst + 12) = *(const float4*)(vp + 12);
  }
  __syncthreads();

  char* kob = kimg + (size_t)bh * 262144 + (size_t)kr * 2 * 4096;
  char* vob = vimg + (size_t)bh * 262144 + (size_t)kr * 2 * 4096;
  #pragma unroll
  for (int it = 0; it < 2; ++it) {     // K fragments: 512 x 16B
    int lin = it * 256 + tid;
    int fi = lin >> 6, l = lin & 63;
    int tt = fi >> 2, st = fi & 3;
    int ky = tt * 32 + (l & 31);
    int e  = st * 16 + (l >> 5) * 8;
    uint4 w = *(const uint4*)(kt + ky * 128 + ((2 * e) ^ ((ky & 7) << 4)));
    *(uint4*)(kob + tt * 4096 + st * 1024 + l * 16) = w;
  }
  #pragma unroll
  for (int it = 0; it < 2; ++it) {     // V fragments: 512 x 16B
    int lin = it * 256 + tid;
    int fi = lin >> 6, l = lin & 63;
    int tt = fi >> 2, f = fi & 3;
    int d  = (f >> 1) * 32 + (l & 31);
    int k0 = tt * 32 + (f & 1) * 16 + (l >> 5) * 8;
    const float* c0 = vt + k0 * 64 + d;
    uint4 w = { pkbf(c0[0],   c0[64]),  pkbf(c0[128], c0[192]),
                pkbf(c0[256], c0[320]), pkbf(c0[384], c0[448]) };
    *(uint4*)(vob + tt * 4096 + f * 1024 + l * 16) = w;
  }
}

// ---- main: 2-wave blocks (backfill queue), wave-autonomous, LPT order ----
__global__ __launch_bounds__(128)
void sattn_frag(const float* __restrict__ Qg, const char* __restrict__ kimg,
                const char* __restrict__ vimg, float* __restrict__ W)
{
  const int id   = blockIdx.x;        // 2560 = 32 bh * 80 pairs ; bh inner -> XCD spread
  const int bh   = id & 31;
  const int pair = id >> 5;
  const int b = bh >> 3, h = bh & 7;

  const int tid  = threadIdx.x;
  const int wave = tid >> 6;          // 0..1
  const int lane = tid & 63;
  const int ln31 = lane & 31;
  const int hi   = lane >> 5;

  const int e   = ORD[pair * 2 + wave];
  const int s   = e & 63, k = e >> 6;
  const int t0u = k * 16;
  const int t1u = (t0u + 16 < s + 1) ? t0u + 16 : s + 1;
  const int G   = s >> 4;
  const int rix = 8 * G * (G + 1) + (s & 15) * (G + 1) + k;
  float* rec = W + ((size_t)bh * NUNIT + rix) * RECSZ32;

  const int q0w = s * 32;
  const int qi  = q0w + ln31;
  const char* kb_img = kimg + (size_t)bh * 262144 + lane * 16;
  const char* vb_img = vimg + (size_t)bh * 262144 + lane * 16;

  // Q fragments, pre-scaled by KS
  short8 qf[4];
  {
    const float* qp = Qg + (((size_t)b * NL + qi) * NH + h) * NE;
    #pragma unroll
    for (int st = 0; st < 4; ++st) {
      const float* qpe = qp + st * 16 + hi * 8;
      union { short8 v; uint32_t u[4]; } f;
      #pragma unroll
      for (int j = 0; j < 4; ++j)
        f.u[j] = pkbf(qpe[2 * j] * KS, qpe[2 * j + 1] * KS);
      qf[st] = f.v;
    }
  }
  short8 onesv;
  {
    union { short8 v; uint32_t u[4]; } o;
    #pragma unroll
    for (int j = 0; j < 4; ++j) o.u[j] = 0x3F803F80u;
    onesv = o.v;
  }

  f32x16 acc0, acc1, accl;
  #pragma unroll
  for (int i = 0; i < 16; ++i) { acc0[i] = 0.f; acc1[i] = 0.f; accl[i] = 0.f; }

  for (int t = t0u; t < t1u; ++t) {
    const char* kp = kb_img + (size_t)t * 4096;
    const char* vp = vb_img + (size_t)t * 4096;
    // 8 coalesced dwordx4 loads (independent; no barriers anywhere)
    short8 a00 = *(const short8*)(vp);
    short8 a01 = *(const short8*)(vp + 1024);
    short8 a10 = *(const short8*)(vp + 2048);
    short8 a11 = *(const short8*)(vp + 3072);
    short8 kf0 = *(const short8*)(kp);
    short8 kf1 = *(const short8*)(kp + 1024);
    short8 kf2 = *(const short8*)(kp + 2048);
    short8 kf3 = *(const short8*)(kp + 3072);

    // S^T = K · (KS*Q)^T
    f32x16 sv;
    #pragma unroll
    for (int i = 0; i < 16; ++i) sv[i] = 0.f;
    sv = __builtin_amdgcn_mfma_f32_32x32x16_bf16(kf0, qf[0], sv, 0, 0, 0);
    sv = __builtin_amdgcn_mfma_f32_32x32x16_bf16(kf1, qf[1], sv, 0, 0, 0);
    sv = __builtin_amdgcn_mfma_f32_32x32x16_bf16(kf2, qf[2], sv, 0, 0, 0);
    sv = __builtin_amdgcn_mfma_f32_32x32x16_bf16(kf3, qf[3], sv, 0, 0, 0);

    // masks + P = exp2(logit), fixed max m=0 (row-sum l via ones-MFMA below)
    const int kv0 = t * 32;
    const int delta = q0w - kv0;
    const int qrelh = (qi - kv0) - 4 * hi;
    if (t == s) {             // diagonal: causal + pow2
      #pragma unroll
      for (int r = 0; r < 16; ++r) {
        const int cr = (r & 3) + 8 * (r >> 2);
        int diff = qrelh - cr;
        float lg = sv[r];
        bool p2 = (diff > 1) & ((diff & (diff - 1)) == 0);
        lg = p2 ? 0.f : lg;
        lg = (diff < 0) ? -__builtin_inff() : lg;
        sv[r] = exp2f(lg);
      }
    } else {
      int pmax = 1 << (31 - __clz(delta + 31));
      if (pmax >= delta - 31) {    // pow2 stride window intersects tile
        #pragma unroll
        for (int r = 0; r < 16; ++r) {
          const int cr = (r & 3) + 8 * (r >> 2);
          int diff = qrelh - cr;
          bool p2 = (diff > 1) & ((diff & (diff - 1)) == 0);
          sv[r] = exp2f(p2 ? 0.f : sv[r]);
        }
      } else {                     // clean: bare exp2
        #pragma unroll
        for (int r = 0; r < 16; ++r) sv[r] = exp2f(sv[r]);
      }
    }

    // pack P -> bf16 fragments (4 shfls)
    uint32_t w0 = pkbf(sv[0],  sv[1]),  w1 = pkbf(sv[2],  sv[3]);
    uint32_t w2 = pkbf(sv[4],  sv[5]),  w3 = pkbf(sv[6],  sv[7]);
    uint32_t w4 = pkbf(sv[8],  sv[9]),  w5 = pkbf(sv[10], sv[11]);
    uint32_t w6 = pkbf(sv[12], sv[13]), w7 = pkbf(sv[14], sv[15]);
    uint32_t y0 = __shfl_xor(hi ? w0 : w2, 32);
    uint32_t y1 = __shfl_xor(hi ? w1 : w3, 32);
    uint32_t y2 = __shfl_xor(hi ? w4 : w6, 32);
    uint32_t y3 = __shfl_xor(hi ? w5 : w7, 32);
    union { short8 v; uint32_t u[4]; } f0, f1;
    if (hi == 0) {
      f0.u[0] = w0; f0.u[1] = w1; f0.u[2] = y0; f0.u[3] = y1;   // keys 0..15
      f1.u[0] = w4; f1.u[1] = w5; f1.u[2] = y2; f1.u[3] = y3;   // keys 16..31
    } else {
      f0.u[0] = y0; f0.u[1] = y1; f0.u[2] = w2; f0.u[3] = w3;
      f1.u[0] = y2; f1.u[1] = y3; f1.u[2] = w6; f1.u[3] = w7;
    }

    // O^T += V^T . P^T ; l row-sum accumulates on the MFMA pipe
    acc0 = __builtin_amdgcn_mfma_f32_32x32x16_bf16(a00, f0.v, acc0, 0, 0, 0);
    acc0 = __builtin_amdgcn_mfma_f32_32x32x16_bf16(a01, f1.v, acc0, 0, 0, 0);
    acc1 = __builtin_amdgcn_mfma_f32_32x32x16_bf16(a10, f0.v, acc1, 0, 0, 0);
    acc1 = __builtin_amdgcn_mfma_f32_32x32x16_bf16(a11, f1.v, acc1, 0, 0, 0);
    accl = __builtin_amdgcn_mfma_f32_32x32x16_bf16(onesv, f0.v, accl, 0, 0, 0);
    accl = __builtin_amdgcn_mfma_f32_32x32x16_bf16(onesv, f1.v, accl, 0, 0, 0);
  }

  // epilogue: unnormalized O^T partial + l (accl[0] = full 32-key row-sum)
  #pragma unroll
  for (int r = 0; r < 16; ++r) {
    int d = (r & 3) + 8 * (r >> 2) + 4 * hi;
    rec[d * 32 + ln31]        = acc0[r];
    rec[(32 + d) * 32 + ln31] = acc1[r];
  }
  if (hi == 0) rec[2048 + ln31] = accl[0];
}

// -------- combine: per (bh, strip): sum <=4 unit records, normalize, transpose --------
__global__ __launch_bounds__(256)
void sattn_combine32(const float* __restrict__ W, float* __restrict__ Og)
{
  const int id = blockIdx.x;             // 2048 = 32 bh * 64 strips
  const int s  = id & 63, bh = id >> 6;
  const int b = bh >> 3, h = bh & 7;
  const int tid = threadIdx.x;

  const int G = s >> 4, i = s & 15;
  const int cum = 8 * G * (G + 1) + i * (G + 1);
  const int nc  = G + 1;
  const float* rec0 = W + ((size_t)bh * NUNIT + cum) * RECSZ32;

  __shared__ float sd[64][33];
  __shared__ float Lq[32];

  {
    int d = tid >> 2, q4 = (tid & 3) * 8;
    float4 a0 = {0,0,0,0}, a1 = {0,0,0,0};
    for (int c = 0; c < nc; ++c) {
      const float* rp = rec0 + (size_t)c * RECSZ32 + d * 32 + q4;
      float4 v0 = *(const float4*)rp, v1 = *(const float4*)(rp + 4);
      a0.x += v0.x; a0.y += v0.y; a0.z += v0.z; a0.w += v0.w;
      a1.x += v1.x; a1.y += v1.y; a1.z += v1.z; a1.w += v1.w;
    }
    sd[d][q4+0] = a0.x; sd[d][q4+1] = a0.y; sd[d][q4+2] = a0.z; sd[d][q4+3] = a0.w;
    sd[d][q4+4] = a1.x; sd[d][q4+5] = a1.y; sd[d][q4+6] = a1.z; sd[d][q4+7] = a1.w;
  }
  if (tid < 32) {
    float a = 0.f;
    for (int c = 0; c < nc; ++c) a += rec0[(size_t)c * RECSZ32 + 2048 + tid];
    Lq[tid] = 1.0f / a;
  }
  __syncthreads();
  {
    int q = tid >> 3, d8 = (tid & 7) * 8;
    float l = Lq[q];
    float4 o0 = { sd[d8+0][q]*l, sd[d8+1][q]*l, sd[d8+2][q]*l, sd[d8+3][q]*l };
    float4 o1 = { sd[d8+4][q]*l, sd[d8+5][q]*l, sd[d8+6][q]*l, sd[d8+7][q]*l };
    float* op = Og + (((size_t)b * NL + s * 32 + q) * NH + h) * ND + d8;
    *(float4*)op = o0; *(float4*)(op + 4) = o1;
  }
}

// ======== fallback path (R6-proven register-staged; used only if ws too small) ========
#define LD(RR) do {                                                         \
    const float* kp_ = kpp + (size_t)(RR) * KSTEP;                          \
    const float* vp_ = vpp + (size_t)(RR) * KSTEP;                          \
    kx0 = *(const float4*)(kp_);      kx1 = *(const float4*)(kp_ + 4);      \
    kx2 = *(const float4*)(kp_ + 8);  kx3 = *(const float4*)(kp_ + 12);     \
    vx0 = *(const float4*)(vp_);               vx1 = *(const float4*)(vp_ + NH*ND); \
    vx2 = *(const float4*)(vp_ + 2*NH*ND);     vx3 = *(const float4*)(vp_ + 3*NH*ND); \
  } while (0)

#define STG(KB, VB) do {                                                    \
    uint4 kwA = { pkbf(kx0.x,kx0.y), pkbf(kx0.z,kx0.w),                     \
                  pkbf(kx1.x,kx1.y), pkbf(kx1.z,kx1.w) };                   \
    uint4 kwB = { pkbf(kx2.x,kx2.y), pkbf(kx2.z,kx2.w),                     \
                  pkbf(kx3.x,kx3.y), pkbf(kx3.z,kx3.w) };                   \
    *(uint4*)((KB) + krow*128 + ( kcol2        ^ kswz)) = kwA;              \
    *(uint4*)((KB) + krow*128 + ((kcol2 + 16)  ^ kswz)) = kwB;              \
    _Pragma("unroll")                                                       \
    for (int j_ = 0; j_ < 4; ++j_) {                                        \
      int d_ = vd0 + j_;                                                    \
      char* vr_ = (VB) + d_*128;                                            \
      int vs_ = (d_ & 7) << 4;                                              \
      *(uint32_t*)(vr_ + ((vk0*2    ) ^ vs_)) = pkbf(vx0[j_], vx1[j_]);     \
      *(uint32_t*)(vr_ + ((vk0*2 + 4) ^ vs_)) = pkbf(vx2[j_], vx3[j_]);     \
    }                                                                       \
  } while (0)

#define COMPUTE(TT, SUB, KB, VB) do {                                       \
    const int kv0_ = (TT) * 32;                                             \
    f32x16 s;                                                               \
    _Pragma("unroll")                                                       \
    for (int i_ = 0; i_ < 16; ++i_) s[i_] = 0.f;                            \
    { const char* kb_ = (const char*)(KB) + ((SUB)*32 + ln31) * 128;        \
      _Pragma("unroll")                                                     \
      for (int st_ = 0; st_ < 4; ++st_) {                                   \
        short8 kf_ = *(const short8*)(kb_ + ((st_*32 + hi*16) ^ rsw));      \
        s = __builtin_amdgcn_mfma_f32_32x32x16_bf16(kf_, qf[st_], s, 0,0,0);\
      } }                                                                   \
    const int delta_ = q0w - kv0_;                                          \
    const int qrelh_ = (qi - kv0_) - 4 * hi;                                \
    if ((TT) == tw) {                                                       \
      _Pragma("unroll")                                                     \
      for (int r_ = 0; r_ < 16; ++r_) {                                     \
        const int cr_ = (r_ & 3) + 8 * (r_ >> 2);                           \
        int diff_ = qrelh_ - cr_;                                           \
        float lg_ = s[r_];                                                  \
        bool p2_ = (diff_ > 1) & ((diff_ & (diff_ - 1)) == 0);              \
        lg_ = p2_ ? 0.f : lg_;                                              \
        lg_ = (diff_ < 0) ? -__builtin_inff() : lg_;                        \
        s[r_] = exp2f(lg_);                                                 \
      }                                                                     \
    } else {                                                                \
      int pmax_ = 1 << (31 - __clz(delta_ + 31));                           \
      if (pmax_ >= delta_ - 31) {                                           \
        _Pragma("unroll")                                                   \
        for (int r_ = 0; r_ < 16; ++r_) {                                   \
          const int cr_ = (r_ & 3) + 8 * (r_ >> 2);                         \
          int diff_ = qrelh_ - cr_;                                         \
          bool p2_ = (diff_ > 1) & ((diff_ & (diff_ - 1)) == 0);            \
          s[r_] = exp2f(p2_ ? 0.f : s[r_]);                                 \
        }                                                                   \
      } else {                                                              \
        _Pragma("unroll")                                                   \
        for (int r_ = 0; r_ < 16; ++r_) s[r_] = exp2f(s[r_]);               \
      }                                                                     \
    }                                                                       \
    uint32_t w0_ = pkbf(s[0],  s[1]),  w1_ = pkbf(s[2],  s[3]);             \
    uint32_t w2_ = pkbf(s[4],  s[5]),  w3_ = pkbf(s[6],  s[7]);             \
    uint32_t w4_ = pkbf(s[8],  s[9]),  w5_ = pkbf(s[10], s[11]);            \
    uint32_t w6_ = pkbf(s[12], s[13]), w7_ = pkbf(s[14], s[15]);            \
    uint32_t y0_ = __shfl_xor(hi ? w0_ : w2_, 32);                          \
    uint32_t y1_ = __shfl_xor(hi ? w1_ : w3_, 32);                          \
    uint32_t y2_ = __shfl_xor(hi ? w4_ : w6_, 32);                          \
    uint32_t y3_ = __shfl_xor(hi ? w5_ : w7_, 32);                          \
    union { short8 v; uint32_t u[4]; } f0_, f1_;                            \
    if (hi == 0) {                                                          \
      f0_.u[0] = w0_; f0_.u[1] = w1_; f0_.u[2] = y0_; f0_.u[3] = y1_;       \
      f1_.u[0] = w4_; f1_.u[1] = w5_; f1_.u[2] = y2_; f1_.u[3] = y3_;       \
    } else {                                                                \
      f0_.u[0] = y0_; f0_.u[1] = y1_; f0_.u[2] = w2_; f0_.u[3] = w3_;       \
      f1_.u[0] = y2_; f1_.u[1] = y3_; f1_.u[2] = w6_; f1_.u[3] = w7_;       \
    }                                                                       \
    { const char* vr0_ = (const char*)(VB) + ln31 * 128;                    \
      const char* vr1_ = (const char*)(VB) + (32 + ln31) * 128;             \
      short8 a00_ = *(const short8*)(vr0_ + (((SUB)*64      + hi*16) ^ rsw));\
      short8 a01_ = *(const short8*)(vr0_ + (((SUB)*64 + 32 + hi*16) ^ rsw));\
      short8 a10_ = *(const short8*)(vr1_ + (((SUB)*64      + hi*16) ^ rsw));\
      short8 a11_ = *(const short8*)(vr1_ + (((SUB)*64 + 32 + hi*16) ^ rsw));\
      acc0 = __builtin_amdgcn_mfma_f32_32x32x16_bf16(a00_, f0_.v, acc0, 0,0,0); \
      acc0 = __builtin_amdgcn_mfma_f32_32x32x16_bf16(a01_, f1_.v, acc0, 0,0,0); \
      acc1 = __builtin_amdgcn_mfma_f32_32x32x16_bf16(a10_, f0_.v, acc1, 0,0,0); \
      acc1 = __builtin_amdgcn_mfma_f32_32x32x16_bf16(a11_, f1_.v, acc1, 0,0,0); \
      accl = __builtin_amdgcn_mfma_f32_32x32x16_bf16(onesv, f0_.v, accl, 0,0,0);\
      accl = __builtin_amdgcn_mfma_f32_32x32x16_bf16(onesv, f1_.v, accl, 0,0,0);\
    }                                                                       \
  } while (0)

__global__ __launch_bounds__(256, 3)
void sattn_mid(const float* __restrict__ Qg, const float* __restrict__ Kg,
               const float* __restrict__ Vg, float* __restrict__ W)
{
  const int id = blockIdx.x;
  const int bh = id & 31;
  const int e  = id >> 5;
  const int g  = TG[e];
  const int t0 = TT0[e], t1 = TT1[e];
  float* rec = W + (size_t)(bh * NCHUNK + TREC[e]) * RECSZ;
  const int b = bh >> 3, h = bh & 7;

  const int tid  = threadIdx.x;
  const int wave = tid >> 6;
  const int lane = tid & 63;
  const int ln31 = lane & 31;
  const int hi   = lane >> 5;

  __shared__ __align__(16) struct { ushort kt[64 * 64]; ushort vt[64 * 64]; } lds;

  const int q0w = g * 128 + wave * 32;
  const int qi  = q0w + ln31;
  const int tw  = 4 * g + wave;
  const int rsw = (ln31 & 7) << 4;

  short8 qf[4];
  {
    const float* qp = Qg + (((size_t)b * NL + qi) * NH + h) * NE;
    #pragma unroll
    for (int st = 0; st < 4; ++st) {
      const float* qpe = qp + st * 16 + hi * 8;
      union { short8 v; uint32_t u[4]; } f;
      #pragma unroll
      for (int j = 0; j < 4; ++j)
        f.u[j] = pkbf(qpe[2 * j] * KS, qpe[2 * j + 1] * KS);
      qf[st] = f.v;
    }
  }
  short8 onesv;
  {
    union { short8 v; uint32_t u[4]; } o;
    #pragma unroll
    for (int j = 0; j < 4; ++j) o.u[j] = 0x3F803F80u;
    onesv = o.v;
  }

  f32x16 acc0, acc1, accl;
  #pragma unroll
  for (int i = 0; i < 16; ++i) { acc0[i] = 0.f; acc1[i] = 0.f; accl[i] = 0.f; }

  const int krow = tid >> 2,        kcol = (tid & 3) * 16;
  const int vk0  = (tid & 15) * 4,  vd0  = (tid >> 4) * 4;
  const int kbase = t0 * 32;
  const float* kpp = Kg + (((size_t)b * NL + kbase + krow) * NH + h) * NE + kcol;
  const float* vpp = Vg + (((size_t)b * NL + kbase + vk0 ) * NH + h) * ND + vd0;
  const int kswz  = (krow & 7) << 4;
  const int kcol2 = kcol * 2;

  float4 kx0, kx1, kx2, kx3, vx0, vx1, vx2, vx3;

  const int nr = (t1 - t0) >> 1;
  LD(0);
  STG((char*)lds.kt, (char*)lds.vt);
  __syncthreads();
  if (nr > 1) LD(1);
  for (int r = 0;;) {
    const int tt = t0 + 2 * r;
    if (tt     <= tw) COMPUTE(tt,     0, (char*)lds.kt, (char*)lds.vt);
    if (tt + 1 <= tw) COMPUTE(tt + 1, 1, (char*)lds.kt, (char*)lds.vt);
    if (++r == nr) break;
    __syncthreads();
    STG((char*)lds.kt, (char*)lds.vt);
    __syncthreads();
    if (r + 1 < nr) LD(r + 1);
  }

  #pragma unroll
  for (int r = 0; r < 16; ++r) {
    int d = (r & 3) + 8 * (r >> 2) + 4 * hi;
    rec[d * 128 + wave * 32 + ln31]        = acc0[r];
    rec[(32 + d) * 128 + wave * 32 + ln31] = acc1[r];
  }
  if (hi == 0) rec[8192 + wave * 32 + ln31] = accl[0];
}

__global__ __launch_bounds__(256)
void sattn_combine(const float* __restrict__ W, float* __restrict__ Og)
{
  const int id = blockIdx.x;
  const int h2 = id & 1, g = (id >> 1) & 15, bh = id >> 5;
  const int b = bh >> 3, h = bh & 7;
  const int tid = threadIdx.x;

  __shared__ float sd[64][67];
  __shared__ float Lq[64];

  const float* rec0 = W + (size_t)(bh * NCHUNK + CUMD[g]) * RECSZ;
  const int nc = NCHD[g];

  #pragma unroll
  for (int rep = 0; rep < 4; ++rep) {
    int d  = rep * 16 + (tid >> 4);
    int q4 = (tid & 15) * 4;
    float4 a = {0.f, 0.f, 0.f, 0.f};
    for (int c = 0; c < nc; ++c) {
      float4 v = *(const float4*)(rec0 + (size_t)c * RECSZ + d * 128 + h2 * 64 + q4);
      a.x += v.x; a.y += v.y; a.z += v.z; a.w += v.w;
    }
    sd[d][q4 + 0] = a.x; sd[d][q4 + 1] = a.y;
    sd[d][q4 + 2] = a.z; sd[d][q4 + 3] = a.w;
  }
  if (tid < 64) {
    float a = 0.f;
    for (int c = 0; c < nc; ++c) a += rec0[(size_t)c * RECSZ + 8192 + h2 * 64 + tid];
    Lq[tid] = 1.0f / a;
  }
  __syncthreads();
  #pragma unroll
  for (int rep = 0; rep < 4; ++rep) {
    int q  = rep * 16 + (tid >> 4);
    int d4 = (tid & 15) * 4;
    float l = Lq[q];
    float4 o = { sd[d4][q] * l, sd[d4 + 1][q] * l, sd[d4 + 2][q] * l, sd[d4 + 3][q] * l };
    *(float4*)(Og + (((size_t)b * NL + g * 128 + h2 * 64 + q) * NH + h) * ND + d4) = o;
  }
}

extern "C" void kernel_launch(void* const* d_in, const int* in_sizes, int n_in,
                              void* d_out, int out_size, void* d_ws, size_t ws_size,
                              hipStream_t stream) {
  const float* Q = (const float*)d_in[0];
  const float* K = (const float*)d_in[1];
  const float* V = (const float*)d_in[2];
  float* O = (float*)d_out;
  const size_t recbytes = (size_t)32 * NUNIT * RECSZ32 * sizeof(float);  // 42.6 MB
  const size_t imgsz    = (size_t)32 * 64 * 4096;                        // 8.39 MB each
  const size_t need_full = recbytes + 2 * imgsz;                         // 59.4 MB (proven)
  const size_t need_mid  = (size_t)32 * NCHUNK * RECSZ * sizeof(float);
  float* W = (float*)d_ws;
  if (ws_size >= need_full) {
    char* kimg = (char*)d_ws + recbytes;
    char* vimg = kimg + imgsz;
    convfrag       <<<dim3(1024), dim3(256), 0, stream>>>(K, V, kimg, vimg);
    sattn_frag     <<<dim3(2560), dim3(128), 0, stream>>>(Q, kimg, vimg, W);
    sattn_combine32<<<dim3(2048), dim3(256), 0, stream>>>(W, O);
  } else {
    sattn_mid      <<<dim3(32 * NCHUNK), dim3(256), 0, stream>>>(Q, K, V, W);
    sattn_combine  <<<dim3(1024), dim3(256), 0, stream>>>(W, O);
  }
}